// Round 6
// baseline (272.331 us; speedup 1.0000x reference)
//
#include <hip/hip_runtime.h>
#include <hip/hip_bf16.h>

// Problem constants
#define NPIX 12544   // 112*112
#define NKV 196      // 14*14
#define CCH 64

typedef _Float16 half2_t __attribute__((ext_vector_type(2)));
typedef __fp16 fp16v2_t __attribute__((ext_vector_type(2)));

#if defined(__has_builtin)
#if __has_builtin(__builtin_amdgcn_fdot2)
#define HAVE_FDOT2 1
#endif
#if __has_builtin(__builtin_amdgcn_cvt_pkrtz)
#define HAVE_PKRTZ 1
#endif
#if __has_builtin(__builtin_amdgcn_exp2f)
#define HAVE_EXP2 1
#endif
#endif

__device__ __forceinline__ float dot2acc(half2_t a, half2_t b, float c) {
#ifdef HAVE_FDOT2
  return __builtin_amdgcn_fdot2(a, b, c, false);
#else
  return c + (float)a.x * (float)b.x + (float)a.y * (float)b.y;
#endif
}

__device__ __forceinline__ half2_t pack2(float a, float b) {
#ifdef HAVE_PKRTZ
  union { fp16v2_t r; half2_t h; } u;
  u.r = __builtin_amdgcn_cvt_pkrtz(a, b);
  return u.h;
#else
  half2_t v; v.x = (_Float16)a; v.y = (_Float16)b; return v;
#endif
}

__device__ __forceinline__ half2_t as_h2(uint u) {
  union { uint v; half2_t h; } c; c.v = u; return c.h;
}
__device__ __forceinline__ uint h2u(half2_t h) {
  union { half2_t h; uint v; } c; c.h = h; return c.v;
}
__device__ __forceinline__ float fexp2(float x) {
#ifdef HAVE_EXP2
  return __builtin_amdgcn_exp2f(x);
#else
  return exp2f(x);
#endif
}

// q scale: hd^-0.5 * log2(e) so the softmax can use raw exp2 (v_exp_f32)
#define QSCALE 0.5100974012336431f

// ---------------------------------------------------------------------------
// Prep kernel: blocks 0..783 transpose x1/x2 [B,C,HW]->[B,HW,C];
// blocks 784..1039 srw [co][ci][ij] -> wt [ij][ci][co];
// block 1040 combined final weights pwc = fpw@pw4, pbc = fpb + fpw@pb4.
__global__ __launch_bounds__(256) void k_prep(
    const float* __restrict__ x1, const float* __restrict__ x2,
    float* __restrict__ x1f, float* __restrict__ x2f,
    const float* __restrict__ s0, const float* __restrict__ s1,
    const float* __restrict__ s2, const float* __restrict__ s3,
    float* __restrict__ wt,
    const float* __restrict__ fpw, const float* __restrict__ fpb,
    const float* __restrict__ pw4, const float* __restrict__ pb4,
    float* __restrict__ pwc, float* __restrict__ pbc) {
  __shared__ float smem[2 * 64 * 65 + 64];
  int blk = blockIdx.x, t = threadIdx.x;
  float (*tile)[65] = (float(*)[65])smem;
  if (blk < 784) {
    int tensor = blk / 392; int rem = blk - tensor * 392;
    int b = rem / 196; int t64 = rem % 196; int n0 = t64 * 64;
    const float* src = tensor ? x2 : x1;
    float* dst = tensor ? x2f : x1f;
    for (int i = 0; i < 16; ++i) {
      int c = i * 4 + (t >> 6);
      int n = t & 63;
      tile[c][n] = src[(b * 64 + c) * NPIX + n0 + n];
    }
    __syncthreads();
    for (int i = 0; i < 16; ++i) {
      int n = i * 4 + (t >> 6);
      int c = t & 63;
      dst[(b * NPIX + n0 + n) * 64 + c] = tile[c][n];
    }
  } else if (blk < 1040) {
    int id = blk - 784; int a = id >> 6; int ci = id & 63;
    const float* s = (a == 0) ? s0 : (a == 1) ? s1 : (a == 2) ? s2 : s3;
    float* d = wt + a * 262144;
    for (int i = 0; i < 16; ++i) {
      int co = i * 4 + (t >> 6);
      int ij = t & 63;
      tile[co][ij] = s[co * 4096 + ci * 64 + ij];
    }
    __syncthreads();
    for (int i = 0; i < 16; ++i) {
      int ij = i * 4 + (t >> 6);
      int co = t & 63;
      d[(ij * 64 + ci) * 64 + co] = tile[co][ij];
    }
  } else {
    float (*A)[65] = (float(*)[65])smem;
    float (*B)[65] = (float(*)[65])(smem + 4160);
    float* bb = smem + 8320;
    for (int i = 0; i < 16; ++i) {
      int idx = i * 256 + t;
      A[idx >> 6][idx & 63] = fpw[idx];
      B[idx >> 6][idx & 63] = pw4[idx];
    }
    if (t < 64) bb[t] = pb4[t];
    __syncthreads();
    int i = t >> 2, jq = t & 3;
    float acc[16];
#pragma unroll
    for (int jj = 0; jj < 16; ++jj) acc[jj] = 0.f;
    for (int k = 0; k < 64; ++k) {
      float a = A[i][k];
#pragma unroll
      for (int jj = 0; jj < 16; ++jj) acc[jj] += a * B[k][jq * 16 + jj];
    }
#pragma unroll
    for (int jj = 0; jj < 16; ++jj) pwc[i * 64 + jq * 16 + jj] = acc[jj];
    if (t < 64) {
      float s = fpb[t];
      for (int k = 0; k < 64; ++k) s += A[t][k] * bb[k];
      pbc[t] = s;
    }
  }
}

// ---------------------------------------------------------------------------
// Fused conv + LayerNorm + KV projection.  grid = 196 blocks, 2 pixels each.
// Conv: 16 k-parts x (4 ij x 64 ci), weights streamed from L2 (float4/co),
// LDS tree-reduce; LN wave-aligned (pixel == wave); KV proj from staged kvw.
__global__ __launch_bounds__(256) void k_convlnkv(
    const float* __restrict__ xf, const float* __restrict__ wt,
    const float* __restrict__ srb,
    const float* __restrict__ lng, const float* __restrict__ lnb,
    const float* __restrict__ kvw,
    _Float16* __restrict__ kbuf, _Float16* __restrict__ vbuf) {
  __shared__ __align__(16) float act[2][64][68];   // [pix][ij][ci] pad-68
  __shared__ __align__(16) float lkvw[128][68];    // [kvco][ci] pad-68
  __shared__ float red[16][2][66];                 // [part][pix][co]
  __shared__ __align__(16) float yn[2][64];
  int blk = blockIdx.x, t = threadIdx.x;
  // stage activations for both pixels (float4, coalesced)
  for (int i = 0; i < 8; ++i) {
    int fi = i * 256 + t;                 // float4 idx over 2*64*16
    int pix = fi >> 10, rem = fi & 1023;
    int ij = rem >> 4, pos = rem & 15;
    int p = blk * 2 + pix, b = p / 196, pi = p % 196;
    int py = pi / 14, px = pi % 14;
    int ii = ij >> 3, jj = ij & 7;
    float4 v = *(const float4*)(xf + ((size_t)(b * NPIX + (8 * py + ii) * 112 + 8 * px + jj) * 64 + pos * 4));
    *(float4*)&act[pix][ij][pos * 4] = v;
  }
  __syncthreads();
  // conv: thread (part, co4): part covers ij = part*4..+3, outputs co4*4..+3
  int co4 = t & 15, part = t >> 4;
  float a0c[4], a1c[4];
  float acc0[4] = {0.f, 0.f, 0.f, 0.f}, acc1[4] = {0.f, 0.f, 0.f, 0.f};
  const float* wb = wt + (part * 4 * 64) * 64 + co4 * 4;
#pragma unroll
  for (int ijl = 0; ijl < 4; ++ijl) {
    int ij = part * 4 + ijl;
    for (int ci = 0; ci < 64; ++ci) {
      float4 w4 = *(const float4*)(wb + (ijl * 64 + ci) * 64);
      float a0 = act[0][ij][ci], a1 = act[1][ij][ci];
      acc0[0] += a0 * w4.x; acc0[1] += a0 * w4.y; acc0[2] += a0 * w4.z; acc0[3] += a0 * w4.w;
      acc1[0] += a1 * w4.x; acc1[1] += a1 * w4.y; acc1[2] += a1 * w4.z; acc1[3] += a1 * w4.w;
    }
  }
  (void)a0c; (void)a1c;
#pragma unroll
  for (int c = 0; c < 4; ++c) {
    red[part][0][co4 * 4 + c] = acc0[c];
    red[part][1][co4 * 4 + c] = acc1[c];
  }
  // stage kvw while red settles (independent)
  for (int i = 0; i < 32; ++i) {
    int idx = i * 256 + t;
    lkvw[idx >> 6][idx & 63] = kvw[idx];
  }
  __syncthreads();
  // LayerNorm: t<128, pixel = wave (t>>6), channel = t&63
  if (t < 128) {
    int pix = t >> 6, c = t & 63;
    float y = 0.f;
#pragma unroll
    for (int k = 0; k < 16; ++k) y += red[k][pix][c];
    y += srb[c];
    float s1 = y, s2 = y * y;
#pragma unroll
    for (int off = 32; off; off >>= 1) { s1 += __shfl_xor(s1, off); s2 += __shfl_xor(s2, off); }
    float mean = s1 * 0.015625f;
    float var = s2 * 0.015625f - mean * mean;
    float rs = rsqrtf(var + 1e-5f);
    yn[pix][c] = (y - mean) * rs * lng[c] + lnb[c];
  }
  __syncthreads();
  // KV projection: thread (pix = t>>7, o = t&127)
  int pix = t >> 7, o = t & 127;
  float acc = 0.f;
#pragma unroll
  for (int c4 = 0; c4 < 16; ++c4) {
    float4 y4 = *(const float4*)&yn[pix][c4 * 4];
    float4 w4 = *(const float4*)&lkvw[o][c4 * 4];
    acc += y4.x * w4.x + y4.y * w4.y + y4.z * w4.z + y4.w * w4.w;
  }
  int p = blk * 2 + pix, b = p / 196, pi = p % 196;
  if (o < 64) {
    int h = o >> 3, d = o & 7;
    kbuf[((b * 8 + h) * 196 + pi) * 8 + d] = (_Float16)acc;   // [b][h][m][d]
  } else {
    int oo = o - 64, h = oo >> 3, d = oo & 7;
    vbuf[((b * 8 + h) * 8 + d) * 196 + pi] = (_Float16)acc;   // [b][h][d][m]
  }
}

// ---------------------------------------------------------------------------
// Fused q-proj + attention core.  grid = 16 bh * 49 tiles = 784, 256 threads.
__global__ __launch_bounds__(256) void k_score(
    const float* __restrict__ xqf, const float* __restrict__ qw,
    const _Float16* __restrict__ kbuf, const _Float16* __restrict__ vbuf,
    float* __restrict__ obuf) {
  __shared__ uint lx[256][33];                // [row][c2] f16 pairs
  __shared__ __align__(16) uint lqw[32][8];   // [c2][j] f16 pairs, scaled
  __shared__ __align__(16) uint4 lK[196];     // K rows, 8 halfs = 16B
  __shared__ __align__(8) uint lV[8 * 98];    // V [d][m-pairs]
  int blk = blockIdx.x;
  int bh = blk / 49, tile = blk - bh * 49;
  int b = bh >> 3, h = bh & 7;
  int t = threadIdx.x;
  const float2* xg = (const float2*)(xqf + ((size_t)b * NPIX + tile * 256) * 64);
  for (int i = 0; i < 32; ++i) {
    int idx = i * 256 + t;                    // float2 index over 256x32
    float2 v = xg[idx];
    lx[idx >> 5][idx & 31] = h2u(pack2(v.x, v.y));
  }
  {
    int j = t & 7, c2 = t >> 3;               // 256 = 32 c2 * 8 j
    float2 wv = *(const float2*)(qw + (h * 8 + j) * 64 + c2 * 2);
    lqw[c2][j] = h2u(pack2(wv.x * QSCALE, wv.y * QSCALE));
  }
  const uint4* kg = (const uint4*)(kbuf + (size_t)bh * 1568);
  if (t < 196) lK[t] = kg[t];
  const uint* vg = (const uint*)(vbuf + (size_t)bh * 1568);
  for (int i = t; i < 784; i += 256) lV[i] = vg[i];
  __syncthreads();
  // q projection for own row (f16 dot2, QSCALE already in weights)
  float q8[8];
#pragma unroll
  for (int j = 0; j < 8; ++j) q8[j] = 0.f;
#pragma unroll
  for (int c2 = 0; c2 < 32; ++c2) {
    half2_t xv = as_h2(lx[t][c2]);
    uint4 w0 = *(const uint4*)&lqw[c2][0];
    uint4 w1 = *(const uint4*)&lqw[c2][4];
    q8[0] = dot2acc(xv, as_h2(w0.x), q8[0]);
    q8[1] = dot2acc(xv, as_h2(w0.y), q8[1]);
    q8[2] = dot2acc(xv, as_h2(w0.z), q8[2]);
    q8[3] = dot2acc(xv, as_h2(w0.w), q8[3]);
    q8[4] = dot2acc(xv, as_h2(w1.x), q8[4]);
    q8[5] = dot2acc(xv, as_h2(w1.y), q8[5]);
    q8[6] = dot2acc(xv, as_h2(w1.z), q8[6]);
    q8[7] = dot2acc(xv, as_h2(w1.w), q8[7]);
  }
  half2_t qh[4];
#pragma unroll
  for (int i = 0; i < 4; ++i) qh[i] = pack2(q8[2 * i], q8[2 * i + 1]);
  // max-free online softmax (scores tiny, exp2-domain), 4 m per iter
  float l = 0.f;
  float o8[8];
#pragma unroll
  for (int j = 0; j < 8; ++j) o8[j] = 0.f;
  for (int m4 = 0; m4 < 49; ++m4) {
    union { uint4 u; half2_t h2[4]; } k0, k1, k2, k3;
    k0.u = lK[4 * m4 + 0]; k1.u = lK[4 * m4 + 1];
    k2.u = lK[4 * m4 + 2]; k3.u = lK[4 * m4 + 3];
    float s0 = 0.f, s1 = 0.f, s2 = 0.f, s3 = 0.f;
#pragma unroll
    for (int i = 0; i < 4; ++i) {
      s0 = dot2acc(qh[i], k0.h2[i], s0);
      s1 = dot2acc(qh[i], k1.h2[i], s1);
      s2 = dot2acc(qh[i], k2.h2[i], s2);
      s3 = dot2acc(qh[i], k3.h2[i], s3);
    }
    float e0 = fexp2(s0), e1 = fexp2(s1), e2 = fexp2(s2), e3 = fexp2(s3);
    l += (e0 + e1) + (e2 + e3);
    half2_t ep01 = pack2(e0, e1), ep23 = pack2(e2, e3);
#pragma unroll
    for (int d = 0; d < 8; ++d) {
      uint2 vv = *(const uint2*)&lV[d * 98 + 2 * m4];
      o8[d] = dot2acc(ep01, as_h2(vv.x), o8[d]);
      o8[d] = dot2acc(ep23, as_h2(vv.y), o8[d]);
    }
  }
  float rl = 1.f / l;
  int n = tile * 256 + t;
  float* op = obuf + ((size_t)b * NPIX + n) * 64 + h * 8;
  float4 w0, w1;
  w0.x = o8[0] * rl; w0.y = o8[1] * rl; w0.z = o8[2] * rl; w0.w = o8[3] * rl;
  w1.x = o8[4] * rl; w1.y = o8[5] * rl; w1.z = o8[6] * rl; w1.w = o8[7] * rl;
  *(float4*)op = w0;
  *(float4*)(op + 4) = w1;
}

// ---------------------------------------------------------------------------
// Out projection + residual: out = (o + xq) @ pw^T + pb.  grid = 392, 256 thr.
__global__ __launch_bounds__(256) void k_outproj(
    const float* __restrict__ obuf, const float* __restrict__ xqf,
    const float* __restrict__ pw, const float* __restrict__ pb,
    float* __restrict__ outb) {
  __shared__ __align__(16) float lt[64][68];
  __shared__ __align__(16) float lw[64][68];   // row map: co -> (co&15)*4 | co>>4
  __shared__ float lpb[64];
  int t = threadIdx.x;
  size_t base = (size_t)blockIdx.x * 64 * 64;
  for (int i = 0; i < 16; ++i) {
    int idx = i * 256 + t;
    int co = idx >> 6, ci = idx & 63;
    int lr = ((co & 15) << 2) | (co >> 4);
    lw[lr][ci] = pw[idx];
  }
  for (int i = 0; i < 16; ++i) {
    int idx = i * 256 + t;
    lt[idx >> 6][idx & 63] = obuf[base + idx] + xqf[base + idx];
  }
  if (t < 64) lpb[t] = pb[t];
  __syncthreads();
  int n = t >> 2, coq = t & 3;    // thread computes co = coq*16 .. +15 for row n
  float acc[16];
#pragma unroll
  for (int k = 0; k < 16; ++k) acc[k] = lpb[coq * 16 + k];
#pragma unroll
  for (int c4 = 0; c4 < 16; ++c4) {
    float4 a4 = *(const float4*)&lt[n][c4 * 4];
#pragma unroll
    for (int k = 0; k < 16; ++k) {
      float4 w4 = *(const float4*)&lw[k * 4 + coq][c4 * 4];
      acc[k] += a4.x * w4.x + a4.y * w4.y + a4.z * w4.z + a4.w * w4.w;
    }
  }
  float* orow = outb + base + (size_t)n * 64 + coq * 16;
#pragma unroll
  for (int k = 0; k < 4; ++k)
    *(float4*)(orow + k * 4) = *(float4*)&acc[k * 4];
}

// ---------------------------------------------------------------------------
// Attention-4 out-proj fused with final projection (combined weights) and
// NCHW transpose-store.  grid = 2*196, 256 threads.
__global__ __launch_bounds__(256) void k_outproj_final(
    const float* __restrict__ obuf, const float* __restrict__ xqf,
    const float* __restrict__ pwc, const float* __restrict__ pbc,
    float* __restrict__ out) {
  __shared__ __align__(16) float lt[64][68];
  __shared__ __align__(16) float lw[64][68];   // row map: co -> (co&15)*4 | co>>4
  __shared__ float lpb[64];
  int id = blockIdx.x;
  int b = id / 196, t64 = id % 196, n0 = t64 * 64;
  int t = threadIdx.x;
  size_t base = ((size_t)b * NPIX + n0) * 64;
  for (int i = 0; i < 16; ++i) {
    int idx = i * 256 + t;
    int co = idx >> 6, ci = idx & 63;
    int lr = ((co & 15) << 2) | (co >> 4);
    lw[lr][ci] = pwc[idx];
  }
  for (int i = 0; i < 16; ++i) {
    int idx = i * 256 + t;
    lt[idx >> 6][idx & 63] = obuf[base + idx] + xqf[base + idx];
  }
  if (t < 64) lpb[t] = pbc[t];
  __syncthreads();
  int n = t >> 2, coq = t & 3;
  float acc[16];
#pragma unroll
  for (int k = 0; k < 16; ++k) acc[k] = lpb[coq * 16 + k];
#pragma unroll
  for (int c4 = 0; c4 < 16; ++c4) {
    float4 a4 = *(const float4*)&lt[n][c4 * 4];
#pragma unroll
    for (int k = 0; k < 16; ++k) {
      float4 w4 = *(const float4*)&lw[k * 4 + coq][c4 * 4];
      acc[k] += a4.x * w4.x + a4.y * w4.y + a4.z * w4.z + a4.w * w4.w;
    }
  }
  __syncthreads();
#pragma unroll
  for (int k = 0; k < 16; ++k) lt[coq * 16 + k][n] = acc[k];
  __syncthreads();
  for (int i = 0; i < 16; ++i) {
    int c = i * 4 + (t >> 6), nn = t & 63;
    out[(size_t)(b * 64 + c) * NPIX + n0 + nn] = lt[c][nn];
  }
}

// ---------------------------------------------------------------------------
extern "C" void kernel_launch(void* const* d_in, const int* in_sizes, int n_in,
                              void* d_out, int out_size, void* d_ws, size_t ws_size,
                              hipStream_t stream) {
  const float* x1 = (const float*)d_in[0];
  const float* x2 = (const float*)d_in[1];
  const float *qw[4], *kvw[4], *pwv[4], *pbv[4], *srw[4], *srb[4], *lng[4], *lnb[4];
  for (int i = 0; i < 4; ++i) {
    const int base = 2 + i * 8;
    qw[i]  = (const float*)d_in[base + 0];
    kvw[i] = (const float*)d_in[base + 1];
    pwv[i] = (const float*)d_in[base + 2];
    pbv[i] = (const float*)d_in[base + 3];
    srw[i] = (const float*)d_in[base + 4];
    srb[i] = (const float*)d_in[base + 5];
    lng[i] = (const float*)d_in[base + 6];
    lnb[i] = (const float*)d_in[base + 7];
  }
  const float* fpw = (const float*)d_in[34];
  const float* fpb = (const float*)d_in[35];
  float* out = (float*)d_out;

  // Workspace layout:
  //   slot0: x1f -> b ; slot1: x2f -> c ; slot2: a
  //   wt (4 MiB), kbuf/vbuf (f16), obuf, pwc/pbc (combined final)
  char* ws = (char*)d_ws;
  const size_t SZ = (size_t)2 * NPIX * 64 * 4;       // 6,422,528 B
  float* slot0 = (float*)(ws);
  float* slot1 = (float*)(ws + SZ);
  float* slot2 = (float*)(ws + 2 * SZ);
  size_t off = 3 * SZ;
  float* wt    = (float*)(ws + off); off += 4u * 1048576;
  _Float16* kbuf = (_Float16*)(ws + off); off += 50176;
  _Float16* vbuf = (_Float16*)(ws + off); off += 50176;
  float* obuf  = (float*)(ws + off); off += SZ;
  float* pwc   = (float*)(ws + off); off += 16384;
  float* pbc   = (float*)(ws + off); off += 256;

  float* xf1 = slot0; float* xf2 = slot1;
  float* abuf = slot2; float* bbuf = slot0; float* cbuf = slot1;

  k_prep<<<1041, 256, 0, stream>>>(x1, x2, xf1, xf2,
                                   srw[0], srw[1], srw[2], srw[3], wt,
                                   fpw, fpb, pwv[3], pbv[3], pwc, pbc);

  const float* xqs[4] = {xf1, xf2, bbuf, abuf};
  const float* kvs[4] = {xf1, abuf, bbuf, cbuf};
  float* outs[3]      = {abuf, bbuf, cbuf};
  for (int i = 0; i < 4; ++i) {
    k_convlnkv<<<196, 256, 0, stream>>>(kvs[i], wt + i * 262144,
                                        srb[i], lng[i], lnb[i], kvw[i], kbuf, vbuf);
    k_score<<<784, 256, 0, stream>>>(xqs[i], qw[i], kbuf, vbuf, obuf);
    if (i < 3)
      k_outproj<<<392, 256, 0, stream>>>(obuf, xqs[i], pwv[i], pbv[i], outs[i]);
    else
      k_outproj_final<<<392, 256, 0, stream>>>(obuf, xqs[3], pwc, pbc, out);
  }
}

// Round 7
// 213.236 us; speedup vs baseline: 1.2771x; 1.2771x over previous
//
#include <hip/hip_runtime.h>
#include <hip/hip_bf16.h>

// Problem constants
#define NPIX 12544   // 112*112
#define NKV 196      // 14*14
#define CCH 64

typedef _Float16 half2_t __attribute__((ext_vector_type(2)));
typedef __fp16 fp16v2_t __attribute__((ext_vector_type(2)));

#if defined(__has_builtin)
#if __has_builtin(__builtin_amdgcn_fdot2)
#define HAVE_FDOT2 1
#endif
#if __has_builtin(__builtin_amdgcn_cvt_pkrtz)
#define HAVE_PKRTZ 1
#endif
#if __has_builtin(__builtin_amdgcn_exp2f)
#define HAVE_EXP2 1
#endif
#endif

__device__ __forceinline__ float dot2acc(half2_t a, half2_t b, float c) {
#ifdef HAVE_FDOT2
  return __builtin_amdgcn_fdot2(a, b, c, false);
#else
  return c + (float)a.x * (float)b.x + (float)a.y * (float)b.y;
#endif
}

__device__ __forceinline__ half2_t pack2(float a, float b) {
#ifdef HAVE_PKRTZ
  union { fp16v2_t r; half2_t h; } u;
  u.r = __builtin_amdgcn_cvt_pkrtz(a, b);
  return u.h;
#else
  half2_t v; v.x = (_Float16)a; v.y = (_Float16)b; return v;
#endif
}

__device__ __forceinline__ half2_t as_h2(uint u) {
  union { uint v; half2_t h; } c; c.v = u; return c.h;
}
__device__ __forceinline__ uint h2u(half2_t h) {
  union { half2_t h; uint v; } c; c.h = h; return c.v;
}
__device__ __forceinline__ float fexp2(float x) {
#ifdef HAVE_EXP2
  return __builtin_amdgcn_exp2f(x);
#else
  return exp2f(x);
#endif
}

// q scale: hd^-0.5 * log2(e) so the softmax can use raw exp2 (v_exp_f32)
#define QSCALE 0.5100974012336431f

// ---------------------------------------------------------------------------
// Prep kernel:
//   blocks 0..783    transpose x1/x2 [B,C,HW]->[B,HW,C]
//   blocks 784..1039 srw [co][ci][ij] -> wt [ij][ci][co]
//   block 1040       combined final weights (fpw@pw4) -> pwh[3] (f16) + pbc
//   blocks 1041..1043 pwv[a] -> pwh[a] f16 packed [c2][co]  (a = blk-1041)
__global__ __launch_bounds__(256) void k_prep(
    const float* __restrict__ x1, const float* __restrict__ x2,
    float* __restrict__ x1f, float* __restrict__ x2f,
    const float* __restrict__ s0, const float* __restrict__ s1,
    const float* __restrict__ s2, const float* __restrict__ s3,
    float* __restrict__ wt,
    const float* __restrict__ fpw, const float* __restrict__ fpb,
    const float* __restrict__ pw4, const float* __restrict__ pb4,
    const float* __restrict__ pw0, const float* __restrict__ pw1,
    const float* __restrict__ pw2,
    uint* __restrict__ pwh, float* __restrict__ pbc) {
  __shared__ float smem[2 * 64 * 65 + 64];
  int blk = blockIdx.x, t = threadIdx.x;
  float (*tile)[65] = (float(*)[65])smem;
  if (blk < 784) {
    int tensor = blk / 392; int rem = blk - tensor * 392;
    int b = rem / 196; int t64 = rem % 196; int n0 = t64 * 64;
    const float* src = tensor ? x2 : x1;
    float* dst = tensor ? x2f : x1f;
    for (int i = 0; i < 16; ++i) {
      int c = i * 4 + (t >> 6);
      int n = t & 63;
      tile[c][n] = src[(b * 64 + c) * NPIX + n0 + n];
    }
    __syncthreads();
    for (int i = 0; i < 16; ++i) {
      int n = i * 4 + (t >> 6);
      int c = t & 63;
      dst[(b * NPIX + n0 + n) * 64 + c] = tile[c][n];
    }
  } else if (blk < 1040) {
    int id = blk - 784; int a = id >> 6; int ci = id & 63;
    const float* s = (a == 0) ? s0 : (a == 1) ? s1 : (a == 2) ? s2 : s3;
    float* d = wt + a * 262144;
    for (int i = 0; i < 16; ++i) {
      int co = i * 4 + (t >> 6);
      int ij = t & 63;
      tile[co][ij] = s[co * 4096 + ci * 64 + ij];
    }
    __syncthreads();
    for (int i = 0; i < 16; ++i) {
      int ij = i * 4 + (t >> 6);
      int co = t & 63;
      d[(ij * 64 + ci) * 64 + co] = tile[co][ij];
    }
  } else if (blk == 1040) {
    float (*A)[65] = (float(*)[65])smem;
    float (*B)[65] = (float(*)[65])(smem + 4160);
    float* bb = smem + 8320;
    for (int i = 0; i < 16; ++i) {
      int idx = i * 256 + t;
      A[idx >> 6][idx & 63] = fpw[idx];
      B[idx >> 6][idx & 63] = pw4[idx];
    }
    if (t < 64) bb[t] = pb4[t];
    __syncthreads();
    int i = t >> 2, jq = t & 3;        // i = final out-channel, cols jq*16..+15
    float acc[16];
#pragma unroll
    for (int jj = 0; jj < 16; ++jj) acc[jj] = 0.f;
    for (int k = 0; k < 64; ++k) {
      float a = A[i][k];
#pragma unroll
      for (int jj = 0; jj < 16; ++jj) acc[jj] += a * B[k][jq * 16 + jj];
    }
    // pack combined weights to f16 [c2][co] layout (slot 3)
#pragma unroll
    for (int m = 0; m < 8; ++m)
      pwh[3 * 2048 + (jq * 8 + m) * 64 + i] = h2u(pack2(acc[2 * m], acc[2 * m + 1]));
    if (t < 64) {
      float s = fpb[t];
      for (int k = 0; k < 64; ++k) s += A[t][k] * bb[k];
      pbc[t] = s;
    }
  } else {
    int a = blk - 1041;                 // 0..2
    const float* pw = (a == 0) ? pw0 : (a == 1) ? pw1 : pw2;
    for (int i = 0; i < 8; ++i) {
      int idx = i * 256 + t;            // 2048 pair-entries
      int co = idx & 63, c2 = idx >> 6;
      float2 wv = *(const float2*)(pw + co * 64 + c2 * 2);
      pwh[a * 2048 + c2 * 64 + co] = h2u(pack2(wv.x, wv.y));
    }
  }
}

// ---------------------------------------------------------------------------
// Reduction conv as GEMM partials.  grid = 49 pixel-groups * 8 k-slices.
// part[s][p][co], p = flat pixel (b*196 + py*14 + px)
// act padded to [8][8][72]: kp-group LDS bank spread 16-way -> 2-way (free).
__global__ __launch_bounds__(256) void k_conv(
    const float* __restrict__ xf, const float* __restrict__ wt,
    float* __restrict__ part) {
  __shared__ __align__(16) float act[8 * 8 * 72];  // [pix][ijl][ci] pad-72
  __shared__ float red[16][8][65];
  int g = blockIdx.x % 49, s = blockIdx.x / 49;
  int t = threadIdx.x;
  for (int q = 0; q < 5; ++q) {
    int fi = q * 256 + t;                // float4 slots over 8*8*18
    if (fi < 1152) {
      int row = fi / 18, pos = fi % 18;
      if (pos < 16) {
        int pix = row >> 3, ijl = row & 7;
        int ij = s * 8 + ijl, ii = ij >> 3, jj = ij & 7;
        int p = g * 8 + pix, b = p / 196, pi = p % 196;
        int py = pi / 14, px = pi % 14;
        *(float4*)&act[row * 72 + pos * 4] =
            *(const float4*)(xf + (size_t)(b * NPIX + (8 * py + ii) * 112 + 8 * px + jj) * 64 + pos * 4);
      }
    }
  }
  __syncthreads();
  int coq = t & 15, kp = t >> 4;           // kp 0..15
  int ijl = kp >> 1, ci0 = (kp & 1) * 32;
  float acc[8][4];
#pragma unroll
  for (int p = 0; p < 8; ++p)
#pragma unroll
    for (int c = 0; c < 4; ++c) acc[p][c] = 0.f;
  const float* wb = wt + ((s * 8 + ijl) * 64 + ci0) * 64 + coq * 4;
  const float* ab = act + ijl * 72 + ci0;
  for (int kk = 0; kk < 32; ++kk) {
    float4 w4 = *(const float4*)(wb + kk * 64);
#pragma unroll
    for (int p = 0; p < 8; ++p) {
      float a = ab[p * 576 + kk];
      acc[p][0] += a * w4.x; acc[p][1] += a * w4.y;
      acc[p][2] += a * w4.z; acc[p][3] += a * w4.w;
    }
  }
#pragma unroll
  for (int p = 0; p < 8; ++p)
#pragma unroll
    for (int c = 0; c < 4; ++c) red[kp][p][coq * 4 + c] = acc[p][c];
  __syncthreads();
  for (int q = 0; q < 2; ++q) {
    int oi = t + q * 256;
    int pix = oi >> 6, co = oi & 63;
    float sum = 0.f;
#pragma unroll
    for (int k = 0; k < 16; ++k) sum += red[k][pix][co];
    int p = g * 8 + pix;
    part[(s * 392 + p) * 64 + co] = sum;
  }
}

// ---------------------------------------------------------------------------
// Reduce conv partials, +bias, LayerNorm, KV projection -> f16 K,V.
// grid = 392 (pixel), 128 threads.
__global__ __launch_bounds__(128) void k_lnkv(
    const float* __restrict__ part, const float* __restrict__ srb,
    const float* __restrict__ lng, const float* __restrict__ lnb,
    const float* __restrict__ kvw,
    _Float16* __restrict__ kbuf, _Float16* __restrict__ vbuf) {
  __shared__ __align__(16) float yn[64];
  __shared__ __align__(16) float4 lkvw[16][128];   // [ci4][co2] vectorized
  int p = blockIdx.x, t = threadIdx.x;
  for (int i = 0; i < 64; ++i) {
    int idx = i * 128 + t;
    int co2 = idx >> 6, ci = idx & 63;
    ((float*)lkvw)[(ci >> 2) * 512 + co2 * 4 + (ci & 3)] = kvw[idx];
  }
  if (t < 64) {
    float y = 0.f;
    for (int s = 0; s < 8; ++s) y += part[(s * 392 + p) * 64 + t];
    y += srb[t];
    float s1 = y, s2 = y * y;
#pragma unroll
    for (int off = 32; off; off >>= 1) { s1 += __shfl_xor(s1, off); s2 += __shfl_xor(s2, off); }
    float mean = s1 * 0.015625f;
    float var = s2 * 0.015625f - mean * mean;
    float rs = rsqrtf(var + 1e-5f);
    yn[t] = (y - mean) * rs * lng[t] + lnb[t];
  }
  __syncthreads();
  float acc = 0.f;
#pragma unroll
  for (int c4 = 0; c4 < 16; ++c4) {
    float4 w4 = lkvw[c4][t];
    float4 y4 = *(const float4*)&yn[c4 * 4];
    acc += y4.x * w4.x + y4.y * w4.y + y4.z * w4.z + y4.w * w4.w;
  }
  int b = p / 196, pi = p % 196;
  int h = (t & 63) >> 3, d = t & 7;
  if (t < 64) kbuf[((b * 8 + h) * 196 + pi) * 8 + d] = (_Float16)acc;          // [b][h][m][d]
  else        vbuf[((b * 8 + h) * 8 + d) * 196 + pi] = (_Float16)acc;          // [b][h][d][m]
}

// ---------------------------------------------------------------------------
// Fused q-proj + attention core + residual + out-projection.
// grid = 2b * 196 tiles (64 rows) = 392 blocks, 512 threads: t = row*8 + head.
// LDS: K [8][197] uint4 (h-stride -> banks h*20, conflict-free),
//      V [8][804] uint  (h-stride -> banks h*4,  conflict-free),
//      sU union: lqw (2048) then lo (64x33 f16-pair rows).
// xq row kept in 32 VGPRs as f16 pairs (reused for residual).
// FINAL variant applies combined (fpw@pw4) weights and stores NCHW.
template <bool FINAL>
__global__ __launch_bounds__(512, 4) void k_score_out(
    const float* __restrict__ xqf, const float* __restrict__ qw,
    const _Float16* __restrict__ kbuf, const _Float16* __restrict__ vbuf,
    const uint* __restrict__ pwh, const float* __restrict__ pb,
    float* __restrict__ outp) {
  __shared__ __align__(16) uint4 sK[8 * 197];
  __shared__ __align__(16) uint sV[8 * 804];
  __shared__ __align__(16) uint sU[64 * 33];
  int blk = blockIdx.x;
  int b = blk / 196, tileb = blk % 196;
  int t = threadIdx.x;
  // --- stage K (all 8 heads of batch b) ---
  const uint4* kg = (const uint4*)kbuf + (size_t)b * 1568;
  for (int i = t; i < 1568; i += 512) {
    int h = i / 196, m = i - h * 196;
    sK[h * 197 + m] = kg[i];
  }
  // --- stage V ---
  const uint* vg = (const uint*)vbuf + (size_t)b * 6272;
  for (int i = t; i < 6272; i += 512) {
    int h = i / 784, r2 = i - h * 784;
    sV[h * 804 + r2] = vg[i];
  }
  // --- stage q-weights f16, QSCALE folded, [c2][co] ---
  for (int i = t; i < 2048; i += 512) {
    int co = i & 63, c2 = i >> 6;
    float2 wv = *(const float2*)(qw + co * 64 + c2 * 2);
    sU[c2 * 64 + co] = h2u(pack2(wv.x * QSCALE, wv.y * QSCALE));
  }
  // --- own xq row -> 32 f16-pair regs ---
  int r = t >> 3, h = t & 7;
  size_t gr = (size_t)b * NPIX + (size_t)tileb * 64 + r;
  uint xh[32];
  const float2* xsrc = (const float2*)(xqf + gr * 64);
#pragma unroll
  for (int i = 0; i < 32; ++i) { float2 v = xsrc[i]; xh[i] = h2u(pack2(v.x, v.y)); }
  __syncthreads();
  // --- q projection (8 ch for own head) ---
  float q8[8];
#pragma unroll
  for (int j = 0; j < 8; ++j) q8[j] = 0.f;
#pragma unroll
  for (int c2 = 0; c2 < 32; ++c2) {
    half2_t xv = as_h2(xh[c2]);
    uint4 w0 = *(const uint4*)&sU[c2 * 64 + h * 8];
    uint4 w1 = *(const uint4*)&sU[c2 * 64 + h * 8 + 4];
    q8[0] = dot2acc(xv, as_h2(w0.x), q8[0]);
    q8[1] = dot2acc(xv, as_h2(w0.y), q8[1]);
    q8[2] = dot2acc(xv, as_h2(w0.z), q8[2]);
    q8[3] = dot2acc(xv, as_h2(w0.w), q8[3]);
    q8[4] = dot2acc(xv, as_h2(w1.x), q8[4]);
    q8[5] = dot2acc(xv, as_h2(w1.y), q8[5]);
    q8[6] = dot2acc(xv, as_h2(w1.z), q8[6]);
    q8[7] = dot2acc(xv, as_h2(w1.w), q8[7]);
  }
  half2_t qh[4];
#pragma unroll
  for (int i = 0; i < 4; ++i) qh[i] = pack2(q8[2 * i], q8[2 * i + 1]);
  __syncthreads();   // lqw reads done; sU becomes lo
  // --- max-free online softmax, 4 m per iter ---
  const uint4* kp = &sK[h * 197];
  const uint* vp = &sV[h * 804];
  float l = 0.f;
  float o8[8];
#pragma unroll
  for (int j = 0; j < 8; ++j) o8[j] = 0.f;
  for (int m4 = 0; m4 < 49; ++m4) {
    union { uint4 u; half2_t h2[4]; } k0, k1, k2, k3;
    k0.u = kp[4 * m4 + 0]; k1.u = kp[4 * m4 + 1];
    k2.u = kp[4 * m4 + 2]; k3.u = kp[4 * m4 + 3];
    float s0 = 0.f, s1 = 0.f, s2 = 0.f, s3 = 0.f;
#pragma unroll
    for (int i = 0; i < 4; ++i) {
      s0 = dot2acc(qh[i], k0.h2[i], s0);
      s1 = dot2acc(qh[i], k1.h2[i], s1);
      s2 = dot2acc(qh[i], k2.h2[i], s2);
      s3 = dot2acc(qh[i], k3.h2[i], s3);
    }
    float e0 = fexp2(s0), e1 = fexp2(s1), e2 = fexp2(s2), e3 = fexp2(s3);
    l += (e0 + e1) + (e2 + e3);
    half2_t ep01 = pack2(e0, e1), ep23 = pack2(e2, e3);
#pragma unroll
    for (int d = 0; d < 8; ++d) {
      uint2 vv = *(const uint2*)&vp[d * 98 + 2 * m4];
      o8[d] = dot2acc(ep01, as_h2(vv.x), o8[d]);
      o8[d] = dot2acc(ep23, as_h2(vv.y), o8[d]);
    }
  }
  float rl = 1.f / l;
#pragma unroll
  for (int j = 0; j < 4; ++j)
    sU[r * 33 + h * 4 + j] = h2u(pack2(o8[2 * j] * rl, o8[2 * j + 1] * rl));
  __syncthreads();
  // --- residual + out-projection: thread (r, cg=h) -> co = cg*8..+7 ---
  int cg = h;
  float acc[8];
#pragma unroll
  for (int k = 0; k < 8; ++k) acc[k] = pb[cg * 8 + k];
#pragma unroll
  for (int c2 = 0; c2 < 32; ++c2) {
    half2_t sv = as_h2(sU[r * 33 + c2]) + as_h2(xh[c2]);
    uint4 w0 = *(const uint4*)&pwh[c2 * 64 + cg * 8];
    uint4 w1 = *(const uint4*)&pwh[c2 * 64 + cg * 8 + 4];
    acc[0] = dot2acc(sv, as_h2(w0.x), acc[0]);
    acc[1] = dot2acc(sv, as_h2(w0.y), acc[1]);
    acc[2] = dot2acc(sv, as_h2(w0.z), acc[2]);
    acc[3] = dot2acc(sv, as_h2(w0.w), acc[3]);
    acc[4] = dot2acc(sv, as_h2(w1.x), acc[4]);
    acc[5] = dot2acc(sv, as_h2(w1.y), acc[5]);
    acc[6] = dot2acc(sv, as_h2(w1.z), acc[6]);
    acc[7] = dot2acc(sv, as_h2(w1.w), acc[7]);
  }
  if (!FINAL) {
    float* orow = outp + gr * 64 + cg * 8;
    float4 v0, v1;
    v0.x = acc[0]; v0.y = acc[1]; v0.z = acc[2]; v0.w = acc[3];
    v1.x = acc[4]; v1.y = acc[5]; v1.z = acc[6]; v1.w = acc[7];
    *(float4*)orow = v0;
    *(float4*)(orow + 4) = v1;
  } else {
    __syncthreads();   // lo reads done; reuse sU for transpose staging (f16)
#pragma unroll
    for (int j = 0; j < 4; ++j)
      sU[r * 33 + cg * 4 + j] = h2u(pack2(acc[2 * j], acc[2 * j + 1]));
    __syncthreads();
    for (int i = t; i < 4096; i += 512) {
      int c = i >> 6, rr = i & 63;
      half2_t pr = as_h2(sU[rr * 33 + (c >> 1)]);
      float val = (c & 1) ? (float)pr.y : (float)pr.x;
      outp[((size_t)(b * 64 + c)) * NPIX + (size_t)tileb * 64 + rr] = val;
    }
  }
}

// ---------------------------------------------------------------------------
extern "C" void kernel_launch(void* const* d_in, const int* in_sizes, int n_in,
                              void* d_out, int out_size, void* d_ws, size_t ws_size,
                              hipStream_t stream) {
  const float* x1 = (const float*)d_in[0];
  const float* x2 = (const float*)d_in[1];
  const float *qw[4], *kvw[4], *pwv[4], *pbv[4], *srw[4], *srb[4], *lng[4], *lnb[4];
  for (int i = 0; i < 4; ++i) {
    const int base = 2 + i * 8;
    qw[i]  = (const float*)d_in[base + 0];
    kvw[i] = (const float*)d_in[base + 1];
    pwv[i] = (const float*)d_in[base + 2];
    pbv[i] = (const float*)d_in[base + 3];
    srw[i] = (const float*)d_in[base + 4];
    srb[i] = (const float*)d_in[base + 5];
    lng[i] = (const float*)d_in[base + 6];
    lnb[i] = (const float*)d_in[base + 7];
  }
  const float* fpw = (const float*)d_in[34];
  const float* fpb = (const float*)d_in[35];
  float* out = (float*)d_out;

  // Workspace layout:
  //   slot0: x1f -> b ; slot1: x2f -> c ; slot2: a
  //   wt (4 MiB), part (0.8 MB), kbuf/vbuf (f16), pwh (f16 out-proj packs), pbc
  char* ws = (char*)d_ws;
  const size_t SZ = (size_t)2 * NPIX * 64 * 4;       // 6,422,528 B
  float* slot0 = (float*)(ws);
  float* slot1 = (float*)(ws + SZ);
  float* slot2 = (float*)(ws + 2 * SZ);
  size_t off = 3 * SZ;
  float* wt    = (float*)(ws + off); off += 4u * 1048576;
  float* part  = (float*)(ws + off); off += 802816;
  _Float16* kbuf = (_Float16*)(ws + off); off += 50176;
  _Float16* vbuf = (_Float16*)(ws + off); off += 50176;
  uint* pwh    = (uint*)(ws + off); off += 4 * 2048 * 4;
  float* pbc   = (float*)(ws + off); off += 256;

  float* xf1 = slot0; float* xf2 = slot1;
  float* abuf = slot2; float* bbuf = slot0; float* cbuf = slot1;

  k_prep<<<1044, 256, 0, stream>>>(x1, x2, xf1, xf2,
                                   srw[0], srw[1], srw[2], srw[3], wt,
                                   fpw, fpb, pwv[3], pbv[3],
                                   pwv[0], pwv[1], pwv[2], pwh, pbc);

  const float* xqs[4] = {xf1, xf2, bbuf, abuf};
  const float* kvs[4] = {xf1, abuf, bbuf, cbuf};
  float* outs[3]      = {abuf, bbuf, cbuf};
  for (int i = 0; i < 4; ++i) {
    k_conv<<<392, 256, 0, stream>>>(kvs[i], wt + i * 262144, part);
    k_lnkv<<<392, 128, 0, stream>>>(part, srb[i], lng[i], lnb[i], kvw[i], kbuf, vbuf);
    if (i < 3)
      k_score_out<false><<<392, 512, 0, stream>>>(xqs[i], qw[i], kbuf, vbuf,
                                                  pwh + i * 2048, pbv[i], outs[i]);
    else
      k_score_out<true><<<392, 512, 0, stream>>>(xqs[3], qw[3], kbuf, vbuf,
                                                 pwh + 3 * 2048, pbc, out);
  }
}

// Round 8
// 199.919 us; speedup vs baseline: 1.3622x; 1.0666x over previous
//
#include <hip/hip_runtime.h>
#include <hip/hip_bf16.h>

// Problem constants
#define NPIX 12544   // 112*112
#define NKV 196      // 14*14
#define CCH 64

typedef _Float16 half2_t __attribute__((ext_vector_type(2)));
typedef __fp16 fp16v2_t __attribute__((ext_vector_type(2)));

#if defined(__has_builtin)
#if __has_builtin(__builtin_amdgcn_fdot2)
#define HAVE_FDOT2 1
#endif
#if __has_builtin(__builtin_amdgcn_cvt_pkrtz)
#define HAVE_PKRTZ 1
#endif
#if __has_builtin(__builtin_amdgcn_exp2f)
#define HAVE_EXP2 1
#endif
#endif

__device__ __forceinline__ float dot2acc(half2_t a, half2_t b, float c) {
#ifdef HAVE_FDOT2
  return __builtin_amdgcn_fdot2(a, b, c, false);
#else
  return c + (float)a.x * (float)b.x + (float)a.y * (float)b.y;
#endif
}

__device__ __forceinline__ half2_t pack2(float a, float b) {
#ifdef HAVE_PKRTZ
  union { fp16v2_t r; half2_t h; } u;
  u.r = __builtin_amdgcn_cvt_pkrtz(a, b);
  return u.h;
#else
  half2_t v; v.x = (_Float16)a; v.y = (_Float16)b; return v;
#endif
}

__device__ __forceinline__ half2_t as_h2(uint u) {
  union { uint v; half2_t h; } c; c.v = u; return c.h;
}
__device__ __forceinline__ uint h2u(half2_t h) {
  union { half2_t h; uint v; } c; c.h = h; return c.v;
}
__device__ __forceinline__ float fexp2(float x) {
#ifdef HAVE_EXP2
  return __builtin_amdgcn_exp2f(x);
#else
  return exp2f(x);
#endif
}

// q scale: hd^-0.5 * log2(e) so the softmax can use raw exp2 (v_exp_f32)
#define QSCALE 0.5100974012336431f

// ---------------------------------------------------------------------------
// Prep kernel:
//   blocks 0..783    transpose x1/x2 [B,C,HW]->[B,HW,C]
//   blocks 784..1039 srw [co][ci][ij] -> wt [ij][ci][co]
//   block 1040       combined final weights (fpw@pw4) -> pwh[3] (f16) + pbc
//   blocks 1041..1043 pwv[a] -> pwh[a] f16 packed [c2][co]  (a = blk-1041)
__global__ __launch_bounds__(256) void k_prep(
    const float* __restrict__ x1, const float* __restrict__ x2,
    float* __restrict__ x1f, float* __restrict__ x2f,
    const float* __restrict__ s0, const float* __restrict__ s1,
    const float* __restrict__ s2, const float* __restrict__ s3,
    float* __restrict__ wt,
    const float* __restrict__ fpw, const float* __restrict__ fpb,
    const float* __restrict__ pw4, const float* __restrict__ pb4,
    const float* __restrict__ pw0, const float* __restrict__ pw1,
    const float* __restrict__ pw2,
    uint* __restrict__ pwh, float* __restrict__ pbc) {
  __shared__ float smem[2 * 64 * 65 + 64];
  int blk = blockIdx.x, t = threadIdx.x;
  float (*tile)[65] = (float(*)[65])smem;
  if (blk < 784) {
    int tensor = blk / 392; int rem = blk - tensor * 392;
    int b = rem / 196; int t64 = rem % 196; int n0 = t64 * 64;
    const float* src = tensor ? x2 : x1;
    float* dst = tensor ? x2f : x1f;
    for (int i = 0; i < 16; ++i) {
      int c = i * 4 + (t >> 6);
      int n = t & 63;
      tile[c][n] = src[(b * 64 + c) * NPIX + n0 + n];
    }
    __syncthreads();
    for (int i = 0; i < 16; ++i) {
      int n = i * 4 + (t >> 6);
      int c = t & 63;
      dst[(b * NPIX + n0 + n) * 64 + c] = tile[c][n];
    }
  } else if (blk < 1040) {
    int id = blk - 784; int a = id >> 6; int ci = id & 63;
    const float* s = (a == 0) ? s0 : (a == 1) ? s1 : (a == 2) ? s2 : s3;
    float* d = wt + a * 262144;
    for (int i = 0; i < 16; ++i) {
      int co = i * 4 + (t >> 6);
      int ij = t & 63;
      tile[co][ij] = s[co * 4096 + ci * 64 + ij];
    }
    __syncthreads();
    for (int i = 0; i < 16; ++i) {
      int ij = i * 4 + (t >> 6);
      int co = t & 63;
      d[(ij * 64 + ci) * 64 + co] = tile[co][ij];
    }
  } else if (blk == 1040) {
    float (*A)[65] = (float(*)[65])smem;
    float (*B)[65] = (float(*)[65])(smem + 4160);
    float* bb = smem + 8320;
    for (int i = 0; i < 16; ++i) {
      int idx = i * 256 + t;
      A[idx >> 6][idx & 63] = fpw[idx];
      B[idx >> 6][idx & 63] = pw4[idx];
    }
    if (t < 64) bb[t] = pb4[t];
    __syncthreads();
    int i = t >> 2, jq = t & 3;        // i = final out-channel, cols jq*16..+15
    float acc[16];
#pragma unroll
    for (int jj = 0; jj < 16; ++jj) acc[jj] = 0.f;
    for (int k = 0; k < 64; ++k) {
      float a = A[i][k];
#pragma unroll
      for (int jj = 0; jj < 16; ++jj) acc[jj] += a * B[k][jq * 16 + jj];
    }
    // pack combined weights to f16 [c2][co] layout (slot 3)
#pragma unroll
    for (int m = 0; m < 8; ++m)
      pwh[3 * 2048 + (jq * 8 + m) * 64 + i] = h2u(pack2(acc[2 * m], acc[2 * m + 1]));
    if (t < 64) {
      float s = fpb[t];
      for (int k = 0; k < 64; ++k) s += A[t][k] * bb[k];
      pbc[t] = s;
    }
  } else {
    int a = blk - 1041;                 // 0..2
    const float* pw = (a == 0) ? pw0 : (a == 1) ? pw1 : pw2;
    for (int i = 0; i < 8; ++i) {
      int idx = i * 256 + t;            // 2048 pair-entries
      int co = idx & 63, c2 = idx >> 6;
      float2 wv = *(const float2*)(pw + co * 64 + c2 * 2);
      pwh[a * 2048 + c2 * 64 + co] = h2u(pack2(wv.x, wv.y));
    }
  }
}

// ---------------------------------------------------------------------------
// Reduction conv as GEMM partials.  grid = 49 pixel-groups * 8 k-slices.
// part[s][p][co], p = flat pixel (b*196 + py*14 + px)
// act padded to [8][8][72]: kp-group LDS bank spread 16-way -> 2-way (free).
__global__ __launch_bounds__(256) void k_conv(
    const float* __restrict__ xf, const float* __restrict__ wt,
    float* __restrict__ part) {
  __shared__ __align__(16) float act[8 * 8 * 72];  // [pix][ijl][ci] pad-72
  __shared__ float red[16][8][65];
  int g = blockIdx.x % 49, s = blockIdx.x / 49;
  int t = threadIdx.x;
  for (int q = 0; q < 5; ++q) {
    int fi = q * 256 + t;                // float4 slots over 8*8*18
    if (fi < 1152) {
      int row = fi / 18, pos = fi % 18;
      if (pos < 16) {
        int pix = row >> 3, ijl = row & 7;
        int ij = s * 8 + ijl, ii = ij >> 3, jj = ij & 7;
        int p = g * 8 + pix, b = p / 196, pi = p % 196;
        int py = pi / 14, px = pi % 14;
        *(float4*)&act[row * 72 + pos * 4] =
            *(const float4*)(xf + (size_t)(b * NPIX + (8 * py + ii) * 112 + 8 * px + jj) * 64 + pos * 4);
      }
    }
  }
  __syncthreads();
  int coq = t & 15, kp = t >> 4;           // kp 0..15
  int ijl = kp >> 1, ci0 = (kp & 1) * 32;
  float acc[8][4];
#pragma unroll
  for (int p = 0; p < 8; ++p)
#pragma unroll
    for (int c = 0; c < 4; ++c) acc[p][c] = 0.f;
  const float* wb = wt + ((s * 8 + ijl) * 64 + ci0) * 64 + coq * 4;
  const float* ab = act + ijl * 72 + ci0;
  for (int kk = 0; kk < 32; ++kk) {
    float4 w4 = *(const float4*)(wb + kk * 64);
#pragma unroll
    for (int p = 0; p < 8; ++p) {
      float a = ab[p * 576 + kk];
      acc[p][0] += a * w4.x; acc[p][1] += a * w4.y;
      acc[p][2] += a * w4.z; acc[p][3] += a * w4.w;
    }
  }
#pragma unroll
  for (int p = 0; p < 8; ++p)
#pragma unroll
    for (int c = 0; c < 4; ++c) red[kp][p][coq * 4 + c] = acc[p][c];
  __syncthreads();
  for (int q = 0; q < 2; ++q) {
    int oi = t + q * 256;
    int pix = oi >> 6, co = oi & 63;
    float sum = 0.f;
#pragma unroll
    for (int k = 0; k < 16; ++k) sum += red[k][pix][co];
    int p = g * 8 + pix;
    part[(s * 392 + p) * 64 + co] = sum;
  }
}

// ---------------------------------------------------------------------------
// Reduce conv partials, +bias, LayerNorm, KV projection -> f16 K,V.
// grid = 392 (pixel), 128 threads.
__global__ __launch_bounds__(128) void k_lnkv(
    const float* __restrict__ part, const float* __restrict__ srb,
    const float* __restrict__ lng, const float* __restrict__ lnb,
    const float* __restrict__ kvw,
    _Float16* __restrict__ kbuf, _Float16* __restrict__ vbuf) {
  __shared__ __align__(16) float yn[64];
  __shared__ __align__(16) float4 lkvw[16][128];   // [ci4][co2] vectorized
  int p = blockIdx.x, t = threadIdx.x;
  for (int i = 0; i < 64; ++i) {
    int idx = i * 128 + t;
    int co2 = idx >> 6, ci = idx & 63;
    ((float*)lkvw)[(ci >> 2) * 512 + co2 * 4 + (ci & 3)] = kvw[idx];
  }
  if (t < 64) {
    float y = 0.f;
    for (int s = 0; s < 8; ++s) y += part[(s * 392 + p) * 64 + t];
    y += srb[t];
    float s1 = y, s2 = y * y;
#pragma unroll
    for (int off = 32; off; off >>= 1) { s1 += __shfl_xor(s1, off); s2 += __shfl_xor(s2, off); }
    float mean = s1 * 0.015625f;
    float var = s2 * 0.015625f - mean * mean;
    float rs = rsqrtf(var + 1e-5f);
    yn[t] = (y - mean) * rs * lng[t] + lnb[t];
  }
  __syncthreads();
  float acc = 0.f;
#pragma unroll
  for (int c4 = 0; c4 < 16; ++c4) {
    float4 w4 = lkvw[c4][t];
    float4 y4 = *(const float4*)&yn[c4 * 4];
    acc += y4.x * w4.x + y4.y * w4.y + y4.z * w4.z + y4.w * w4.w;
  }
  int b = p / 196, pi = p % 196;
  int h = (t & 63) >> 3, d = t & 7;
  if (t < 64) kbuf[((b * 8 + h) * 196 + pi) * 8 + d] = (_Float16)acc;          // [b][h][m][d]
  else        vbuf[((b * 8 + h) * 8 + d) * 196 + pi] = (_Float16)acc;          // [b][h][d][m]
}

// ---------------------------------------------------------------------------
// Fused q-proj + attention core + residual + out-projection.
// grid = 392 blocks (64-row tiles), 256 threads: t = r*8 + h, r in [0,32).
// EACH THREAD HANDLES 2 ROWS (r, r+32): the 12 LDS broadcasts per 4-m iter
// are amortized over 2 rows (round-7 PMC: LDS-issue pipe was the bottleneck).
// LDS: K [8][197] uint4 (bank h*20), V [8][804] uint (bank h*4), sU union.
template <bool FINAL>
__global__ __launch_bounds__(256, 2) void k_score_out(
    const float* __restrict__ xqf, const float* __restrict__ qw,
    const _Float16* __restrict__ kbuf, const _Float16* __restrict__ vbuf,
    const uint* __restrict__ pwh, const float* __restrict__ pb,
    float* __restrict__ outp) {
  __shared__ __align__(16) uint4 sK[8 * 197];
  __shared__ __align__(16) uint sV[8 * 804];
  __shared__ __align__(16) uint sU[64 * 33];
  int blk = blockIdx.x;
  int b = blk / 196, tileb = blk % 196;
  int t = threadIdx.x;
  // --- stage K (all 8 heads of batch b) ---
  const uint4* kg = (const uint4*)kbuf + (size_t)b * 1568;
  for (int i = t; i < 1568; i += 256) {
    int h = i / 196, m = i - h * 196;
    sK[h * 197 + m] = kg[i];
  }
  // --- stage V ---
  const uint* vg = (const uint*)vbuf + (size_t)b * 6272;
  for (int i = t; i < 6272; i += 256) {
    int h = i / 784, r2 = i - h * 784;
    sV[h * 804 + r2] = vg[i];
  }
  // --- stage q-weights f16, QSCALE folded, [c2][co] ---
  for (int i = t; i < 2048; i += 256) {
    int co = i & 63, c2 = i >> 6;
    float2 wv = *(const float2*)(qw + co * 64 + c2 * 2);
    sU[c2 * 64 + co] = h2u(pack2(wv.x * QSCALE, wv.y * QSCALE));
  }
  // --- own 2 xq rows -> f16-pair regs ---
  int r = t >> 3, h = t & 7;
  size_t gr0 = (size_t)b * NPIX + (size_t)tileb * 64 + r;
  size_t gr1 = gr0 + 32;
  uint xh0[32], xh1[32];
  {
    const float2* x0 = (const float2*)(xqf + gr0 * 64);
    const float2* x1 = (const float2*)(xqf + gr1 * 64);
#pragma unroll
    for (int i = 0; i < 32; ++i) { float2 v = x0[i]; xh0[i] = h2u(pack2(v.x, v.y)); }
#pragma unroll
    for (int i = 0; i < 32; ++i) { float2 v = x1[i]; xh1[i] = h2u(pack2(v.x, v.y)); }
  }
  __syncthreads();
  // --- q projection for both rows (weight reads shared) ---
  float q80[8], q81[8];
#pragma unroll
  for (int j = 0; j < 8; ++j) { q80[j] = 0.f; q81[j] = 0.f; }
#pragma unroll
  for (int c2 = 0; c2 < 32; ++c2) {
    half2_t xv0 = as_h2(xh0[c2]), xv1 = as_h2(xh1[c2]);
    uint4 w0 = *(const uint4*)&sU[c2 * 64 + h * 8];
    uint4 w1 = *(const uint4*)&sU[c2 * 64 + h * 8 + 4];
    q80[0] = dot2acc(xv0, as_h2(w0.x), q80[0]); q81[0] = dot2acc(xv1, as_h2(w0.x), q81[0]);
    q80[1] = dot2acc(xv0, as_h2(w0.y), q80[1]); q81[1] = dot2acc(xv1, as_h2(w0.y), q81[1]);
    q80[2] = dot2acc(xv0, as_h2(w0.z), q80[2]); q81[2] = dot2acc(xv1, as_h2(w0.z), q81[2]);
    q80[3] = dot2acc(xv0, as_h2(w0.w), q80[3]); q81[3] = dot2acc(xv1, as_h2(w0.w), q81[3]);
    q80[4] = dot2acc(xv0, as_h2(w1.x), q80[4]); q81[4] = dot2acc(xv1, as_h2(w1.x), q81[4]);
    q80[5] = dot2acc(xv0, as_h2(w1.y), q80[5]); q81[5] = dot2acc(xv1, as_h2(w1.y), q81[5]);
    q80[6] = dot2acc(xv0, as_h2(w1.z), q80[6]); q81[6] = dot2acc(xv1, as_h2(w1.z), q81[6]);
    q80[7] = dot2acc(xv0, as_h2(w1.w), q80[7]); q81[7] = dot2acc(xv1, as_h2(w1.w), q81[7]);
  }
  half2_t qh0[4], qh1[4];
#pragma unroll
  for (int i = 0; i < 4; ++i) {
    qh0[i] = pack2(q80[2 * i], q80[2 * i + 1]);
    qh1[i] = pack2(q81[2 * i], q81[2 * i + 1]);
  }
  __syncthreads();   // lqw reads done; sU becomes lo
  // --- max-free online softmax, 4 m per iter, 2 rows per thread ---
  const uint4* kp = &sK[h * 197];
  const uint* vp = &sV[h * 804];
  float l0 = 0.f, l1 = 0.f;
  float o80[8], o81[8];
#pragma unroll
  for (int j = 0; j < 8; ++j) { o80[j] = 0.f; o81[j] = 0.f; }
  for (int m4 = 0; m4 < 49; ++m4) {
    union { uint4 u; half2_t h2[4]; } k0, k1, k2, k3;
    k0.u = kp[4 * m4 + 0]; k1.u = kp[4 * m4 + 1];
    k2.u = kp[4 * m4 + 2]; k3.u = kp[4 * m4 + 3];
    float s00 = 0.f, s01 = 0.f, s02 = 0.f, s03 = 0.f;
    float s10 = 0.f, s11 = 0.f, s12 = 0.f, s13 = 0.f;
#pragma unroll
    for (int i = 0; i < 4; ++i) {
      s00 = dot2acc(qh0[i], k0.h2[i], s00); s10 = dot2acc(qh1[i], k0.h2[i], s10);
      s01 = dot2acc(qh0[i], k1.h2[i], s01); s11 = dot2acc(qh1[i], k1.h2[i], s11);
      s02 = dot2acc(qh0[i], k2.h2[i], s02); s12 = dot2acc(qh1[i], k2.h2[i], s12);
      s03 = dot2acc(qh0[i], k3.h2[i], s03); s13 = dot2acc(qh1[i], k3.h2[i], s13);
    }
    float e00 = fexp2(s00), e01 = fexp2(s01), e02 = fexp2(s02), e03 = fexp2(s03);
    float e10 = fexp2(s10), e11 = fexp2(s11), e12 = fexp2(s12), e13 = fexp2(s13);
    l0 += (e00 + e01) + (e02 + e03);
    l1 += (e10 + e11) + (e12 + e13);
    half2_t ep01_0 = pack2(e00, e01), ep23_0 = pack2(e02, e03);
    half2_t ep01_1 = pack2(e10, e11), ep23_1 = pack2(e12, e13);
#pragma unroll
    for (int d = 0; d < 8; ++d) {
      uint2 vv = *(const uint2*)&vp[d * 98 + 2 * m4];
      half2_t va = as_h2(vv.x), vb = as_h2(vv.y);
      o80[d] = dot2acc(ep01_0, va, o80[d]);
      o80[d] = dot2acc(ep23_0, vb, o80[d]);
      o81[d] = dot2acc(ep01_1, va, o81[d]);
      o81[d] = dot2acc(ep23_1, vb, o81[d]);
    }
  }
  float rl0 = 1.f / l0, rl1 = 1.f / l1;
#pragma unroll
  for (int j = 0; j < 4; ++j) {
    sU[r * 33 + h * 4 + j] = h2u(pack2(o80[2 * j] * rl0, o80[2 * j + 1] * rl0));
    sU[(r + 32) * 33 + h * 4 + j] = h2u(pack2(o81[2 * j] * rl1, o81[2 * j + 1] * rl1));
  }
  __syncthreads();
  // --- residual + out-projection: thread (r, cg=h), both rows ---
  int cg = h;
  float acc0[8], acc1[8];
#pragma unroll
  for (int k = 0; k < 8; ++k) { acc0[k] = pb[cg * 8 + k]; acc1[k] = acc0[k]; }
#pragma unroll
  for (int c2 = 0; c2 < 32; ++c2) {
    half2_t sv0 = as_h2(sU[r * 33 + c2]) + as_h2(xh0[c2]);
    half2_t sv1 = as_h2(sU[(r + 32) * 33 + c2]) + as_h2(xh1[c2]);
    uint4 w0 = *(const uint4*)&pwh[c2 * 64 + cg * 8];
    uint4 w1 = *(const uint4*)&pwh[c2 * 64 + cg * 8 + 4];
    acc0[0] = dot2acc(sv0, as_h2(w0.x), acc0[0]); acc1[0] = dot2acc(sv1, as_h2(w0.x), acc1[0]);
    acc0[1] = dot2acc(sv0, as_h2(w0.y), acc0[1]); acc1[1] = dot2acc(sv1, as_h2(w0.y), acc1[1]);
    acc0[2] = dot2acc(sv0, as_h2(w0.z), acc0[2]); acc1[2] = dot2acc(sv1, as_h2(w0.z), acc1[2]);
    acc0[3] = dot2acc(sv0, as_h2(w0.w), acc0[3]); acc1[3] = dot2acc(sv1, as_h2(w0.w), acc1[3]);
    acc0[4] = dot2acc(sv0, as_h2(w1.x), acc0[4]); acc1[4] = dot2acc(sv1, as_h2(w1.x), acc1[4]);
    acc0[5] = dot2acc(sv0, as_h2(w1.y), acc0[5]); acc1[5] = dot2acc(sv1, as_h2(w1.y), acc1[5]);
    acc0[6] = dot2acc(sv0, as_h2(w1.z), acc0[6]); acc1[6] = dot2acc(sv1, as_h2(w1.z), acc1[6]);
    acc0[7] = dot2acc(sv0, as_h2(w1.w), acc0[7]); acc1[7] = dot2acc(sv1, as_h2(w1.w), acc1[7]);
  }
  if (!FINAL) {
    float* o0 = outp + gr0 * 64 + cg * 8;
    float* o1 = outp + gr1 * 64 + cg * 8;
    float4 v0, v1;
    v0.x = acc0[0]; v0.y = acc0[1]; v0.z = acc0[2]; v0.w = acc0[3];
    v1.x = acc0[4]; v1.y = acc0[5]; v1.z = acc0[6]; v1.w = acc0[7];
    *(float4*)o0 = v0; *(float4*)(o0 + 4) = v1;
    v0.x = acc1[0]; v0.y = acc1[1]; v0.z = acc1[2]; v0.w = acc1[3];
    v1.x = acc1[4]; v1.y = acc1[5]; v1.z = acc1[6]; v1.w = acc1[7];
    *(float4*)o1 = v0; *(float4*)(o1 + 4) = v1;
  } else {
    __syncthreads();   // lo reads done; reuse sU for transpose staging (f16)
#pragma unroll
    for (int j = 0; j < 4; ++j) {
      sU[r * 33 + cg * 4 + j] = h2u(pack2(acc0[2 * j], acc0[2 * j + 1]));
      sU[(r + 32) * 33 + cg * 4 + j] = h2u(pack2(acc1[2 * j], acc1[2 * j + 1]));
    }
    __syncthreads();
    for (int i = t; i < 4096; i += 256) {
      int c = i >> 6, rr = i & 63;
      half2_t pr = as_h2(sU[rr * 33 + (c >> 1)]);
      float val = (c & 1) ? (float)pr.y : (float)pr.x;
      outp[((size_t)(b * 64 + c)) * NPIX + (size_t)tileb * 64 + rr] = val;
    }
  }
}

// ---------------------------------------------------------------------------
extern "C" void kernel_launch(void* const* d_in, const int* in_sizes, int n_in,
                              void* d_out, int out_size, void* d_ws, size_t ws_size,
                              hipStream_t stream) {
  const float* x1 = (const float*)d_in[0];
  const float* x2 = (const float*)d_in[1];
  const float *qw[4], *kvw[4], *pwv[4], *pbv[4], *srw[4], *srb[4], *lng[4], *lnb[4];
  for (int i = 0; i < 4; ++i) {
    const int base = 2 + i * 8;
    qw[i]  = (const float*)d_in[base + 0];
    kvw[i] = (const float*)d_in[base + 1];
    pwv[i] = (const float*)d_in[base + 2];
    pbv[i] = (const float*)d_in[base + 3];
    srw[i] = (const float*)d_in[base + 4];
    srb[i] = (const float*)d_in[base + 5];
    lng[i] = (const float*)d_in[base + 6];
    lnb[i] = (const float*)d_in[base + 7];
  }
  const float* fpw = (const float*)d_in[34];
  const float* fpb = (const float*)d_in[35];
  float* out = (float*)d_out;

  // Workspace layout:
  //   slot0: x1f -> b ; slot1: x2f -> c ; slot2: a
  //   wt (4 MiB), part (0.8 MB), kbuf/vbuf (f16), pwh (f16 out-proj packs), pbc
  char* ws = (char*)d_ws;
  const size_t SZ = (size_t)2 * NPIX * 64 * 4;       // 6,422,528 B
  float* slot0 = (float*)(ws);
  float* slot1 = (float*)(ws + SZ);
  float* slot2 = (float*)(ws + 2 * SZ);
  size_t off = 3 * SZ;
  float* wt    = (float*)(ws + off); off += 4u * 1048576;
  float* part  = (float*)(ws + off); off += 802816;
  _Float16* kbuf = (_Float16*)(ws + off); off += 50176;
  _Float16* vbuf = (_Float16*)(ws + off); off += 50176;
  uint* pwh    = (uint*)(ws + off); off += 4 * 2048 * 4;
  float* pbc   = (float*)(ws + off); off += 256;

  float* xf1 = slot0; float* xf2 = slot1;
  float* abuf = slot2; float* bbuf = slot0; float* cbuf = slot1;

  k_prep<<<1044, 256, 0, stream>>>(x1, x2, xf1, xf2,
                                   srw[0], srw[1], srw[2], srw[3], wt,
                                   fpw, fpb, pwv[3], pbv[3],
                                   pwv[0], pwv[1], pwv[2], pwh, pbc);

  const float* xqs[4] = {xf1, xf2, bbuf, abuf};
  const float* kvs[4] = {xf1, abuf, bbuf, cbuf};
  float* outs[3]      = {abuf, bbuf, cbuf};
  for (int i = 0; i < 4; ++i) {
    k_conv<<<392, 256, 0, stream>>>(kvs[i], wt + i * 262144, part);
    k_lnkv<<<392, 128, 0, stream>>>(part, srb[i], lng[i], lnb[i], kvw[i], kbuf, vbuf);
    if (i < 3)
      k_score_out<false><<<392, 256, 0, stream>>>(xqs[i], qw[i], kbuf, vbuf,
                                                  pwh + i * 2048, pbv[i], outs[i]);
    else
      k_score_out<true><<<392, 256, 0, stream>>>(xqs[3], qw[3], kbuf, vbuf,
                                                 pwh + 3 * 2048, pbc, out);
  }
}